// Round 7
// baseline (344.918 us; speedup 1.0000x reference)
//
#include <hip/hip_runtime.h>

typedef __bf16 bf16x8 __attribute__((ext_vector_type(8)));
typedef short  s16x8  __attribute__((ext_vector_type(8)));
typedef float  f32x4  __attribute__((ext_vector_type(4)));

#define DEVINL __device__ __forceinline__

DEVINL unsigned short f2bf(float f) {
  unsigned int u = __builtin_bit_cast(unsigned int, f);
  u += 0x7fffu + ((u >> 16) & 1u);   // round-to-nearest-even
  return (unsigned short)(u >> 16);
}

DEVINL void async16(const void* g, void* l) {
  __builtin_amdgcn_global_load_lds(
      (const __attribute__((address_space(1))) unsigned int*)g,
      (__attribute__((address_space(3))) unsigned int*)l, 16, 0, 0);
}

// ---------------- conversion kernels ----------------

__global__ void cvt_f32_bf16(const float* __restrict__ in,
                             unsigned short* __restrict__ out, int n4) {
  int i = blockIdx.x * blockDim.x + threadIdx.x;
  int stride = gridDim.x * blockDim.x;
  for (; i < n4; i += stride) {
    float4 v = ((const float4*)in)[i];
    ushort4 o;
    o.x = f2bf(v.x); o.y = f2bf(v.y); o.z = f2bf(v.z); o.w = f2bf(v.w);
    ((ushort4*)out)[i] = o;
  }
}

// in: [R][C] fp32  ->  out: [C][R] bf16
__global__ void transpose_cvt(const float* __restrict__ in,
                              unsigned short* __restrict__ out, int R, int C) {
  __shared__ unsigned short tile[32][33];
  int bc = blockIdx.x * 32, br = blockIdx.y * 32;
  int tx = threadIdx.x & 31, ty = threadIdx.x >> 5;
#pragma unroll
  for (int i = 0; i < 32; i += 8)
    tile[ty + i][tx] = f2bf(in[(size_t)(br + ty + i) * C + (bc + tx)]);
  __syncthreads();
#pragma unroll
  for (int i = 0; i < 32; i += 8)
    out[(size_t)(bc + ty + i) * R + (br + tx)] = tile[tx][ty + i];
}

__global__ void qconst(const float* __restrict__ theta,
                       const float* __restrict__ wre,
                       const float* __restrict__ wim,
                       float* __restrict__ c1, int n) {
  int i = blockIdx.x * blockDim.x + threadIdx.x;
  if (i < n) {
    float t = theta[i];
    c1[i] = (cosf(t) * wre[i] + sinf(t) * wim[i]) * wim[i] * 0.1f;
  }
}

// ---------- GEMM, B-in-registers: C = A[M][K] * Bt[N][K]^T ----------
// BM x 256 tile, BK=64, 8 waves (2M x 4N). A staged via global_load_lds into
// double-buffered XOR-swizzled LDS (A only -> LDS traffic halved vs R4).
// B fragments loaded straight global->VGPR (16 B/lane contiguous; 64 B per
// 4-lane group; W panels are L2-resident) into a one-tile register double
// buffer (bA/bB, compile-time name swap -> no runtime indexing).
// ONE barrier + lgkm0 + vmcnt(8) per K-tile:
//  - window T reads bufA[T&1]; stages A(T+1) -> bufA[~T&1]; loads b(T+1).
//  - stage target bufA[~T&1] was last READ in window T-1; those reads
//    drained by window T-1's lgkmcnt(0) BEFORE its closing barrier, and the
//    stage issues only AFTER that barrier -> no WAR hazard with one barrier.
//  - A(T+1) arrival: issued in window T (A-stages before b-loads, so queue
//    = [A x LA, b x 8]); end-of-window vmcnt(8) drains exactly the A stages;
//    the barrier publishes them.
//  - b(T) register loads are ordinary loads: the compiler inserts exact
//    vmcnt waits before their first MFMA use (b(T+1) stays in flight).
// Single barrier per tile lets waves skew -> one wave's ds_reads overlap
// another's MFMAs instead of chip-wide lockstep alternation.

template <int BM, int NT, bool FUSED>
__global__ __launch_bounds__(512, 2) void gemmbr(
    const unsigned short* __restrict__ A,
    const unsigned short* __restrict__ Bt,
    const float* __restrict__ bias,
    const float* __restrict__ theta,
    const float* __restrict__ c1,
    void* __restrict__ Cout,
    int N, int nTilesN) {
  constexpr int K      = NT * 64;
  constexpr int WROWS  = BM / 2;        // per-wave output rows
  constexpr int M_REP  = WROWS / 16;    // 8 (BM=256) or 4 (BM=128)
  constexpr int MH     = M_REP / 2;
  constexpr int ABYTES = BM * 128;      // A bytes per buffer
  constexpr int LA     = ABYTES / 8192; // per-thread A stage-loads per K-tile
  static_assert(LA == 4 || LA == 2, "geometry");

  __shared__ __align__(16) char lds[2 * ABYTES];

  // bijective XCD swizzle (grid % 8 == 0 for both instantiations)
  int nwg = gridDim.x;
  int wg = blockIdx.x;
  int sw = (wg & 7) * (nwg >> 3) + (wg >> 3);
  int rowBase = (sw / nTilesN) * BM;
  int colBase = (sw % nTilesN) * 256;

  const int t = threadIdx.x;
  const int lane = t & 63;
  const int wid = t >> 6;
  const int wr = wid >> 2, wc = wid & 3;   // 2M x 4N waves
  const int lr = lane & 15;
  const int lg = lane >> 4;                // 0..3
  const int r7 = lane & 7;

  // A staging source (pre-swizzled global address, linear LDS dest)
  const int arow = t >> 3;                             // 0..63
  const int acolB = ((t & 7) * 16) ^ ((arow & 7) << 4);
  const unsigned short* aSrc = A + (size_t)(rowBase + arow) * K + (acolB >> 1);

  // swizzled A ds_read base (bytes); frag mi: +mi*2048, ks: ^ (ks*64)
  const int aRd = (wr * WROWS + lr) * 128 + ((lg ^ r7) * 16);

  // B global fragment base: frag f (cols f*16), ks -> +f*16*K + ks*32 elems
  const unsigned short* bBase =
      Bt + (size_t)(colBase + wc * 64 + lr) * K + lg * 8;

  f32x4 acc[M_REP][4] = {};
  bf16x8 a0[MH][2], a1[MH][2], bA[4][2], bB[4][2];

#define STAGE_A(T1, BO, j)                                                  \
  async16(aSrc + ((size_t)(j) * 64 * K + (size_t)(T1) * 64),                \
          &lds[(BO) + (j) * 8192 + t * 16])

#define LOADB(BS, T2)                                                       \
  _Pragma("unroll") for (int f = 0; f < 4; ++f)                             \
  _Pragma("unroll") for (int ks = 0; ks < 2; ++ks)                          \
    BS[f][ks] = __builtin_bit_cast(bf16x8, *(const s16x8*)(bBase +          \
        (size_t)f * 16 * K + (size_t)(T2) * 64 + ks * 32))

#define LDS_A0(BO)                                                          \
  _Pragma("unroll") for (int mi = 0; mi < MH; ++mi)                         \
  _Pragma("unroll") for (int ks = 0; ks < 2; ++ks)                          \
    a0[mi][ks] = __builtin_bit_cast(bf16x8, *(const s16x8*)&lds[            \
        (BO) + ((aRd + mi * 2048) ^ (ks * 64))])
#define LDS_A1(BO)                                                          \
  _Pragma("unroll") for (int mi = 0; mi < MH; ++mi)                         \
  _Pragma("unroll") for (int ks = 0; ks < 2; ++ks)                          \
    a1[mi][ks] = __builtin_bit_cast(bf16x8, *(const s16x8*)&lds[            \
        (BO) + ((aRd + (MH + mi) * 2048) ^ (ks * 64))])

#define QUAD(AF, MOFF, BS, nh)                                              \
  __builtin_amdgcn_s_setprio(1);                                            \
  _Pragma("unroll") for (int mi = 0; mi < MH; ++mi)                         \
  _Pragma("unroll") for (int nn = 0; nn < 2; ++nn)                          \
  _Pragma("unroll") for (int ks = 0; ks < 2; ++ks)                          \
    acc[(MOFF) + mi][(nh) * 2 + nn] =                                       \
        __builtin_amdgcn_mfma_f32_16x16x32_bf16(                            \
            AF[mi][ks], BS[(nh) * 2 + nn][ks],                              \
            acc[(MOFF) + mi][(nh) * 2 + nn], 0, 0, 0);                      \
  __builtin_amdgcn_s_setprio(0)

#define BAR() __builtin_amdgcn_s_barrier()

#define WINDOW(T, PAR, BCUR, BNXT) do {                                     \
    LDS_A0((PAR) * ABYTES);                                                 \
    LDS_A1((PAR) * ABYTES);                                                 \
    if ((T) + 1 < NT) {                                                     \
      _Pragma("unroll") for (int j = 0; j < LA; ++j)                        \
        STAGE_A((T) + 1, ((PAR) ^ 1) * ABYTES, j);                          \
      LOADB(BNXT, (T) + 1);                                                 \
    }                                                                       \
    QUAD(a0, 0, BCUR, 0);                                                   \
    QUAD(a0, 0, BCUR, 1);                                                   \
    QUAD(a1, MH, BCUR, 0);                                                  \
    QUAD(a1, MH, BCUR, 1);                                                  \
    asm volatile("s_waitcnt lgkmcnt(0)" ::: "memory");                      \
    asm volatile("s_waitcnt vmcnt(8)" ::: "memory");                        \
    BAR();                                                                  \
  } while (0)

  // prologue: stage A(0), load b(0); drain A stages (b may fly), barrier
#pragma unroll
  for (int j = 0; j < LA; ++j) STAGE_A(0, 0, j);
  LOADB(bA, 0);
  asm volatile("s_waitcnt vmcnt(8)" ::: "memory");
  BAR();

  for (int T = 0; T < NT; T += 2) {   // NT even (16, 64)
    WINDOW(T, 0, bA, bB);
    WINDOW(T + 1, 1, bB, bA);
  }

#undef WINDOW
#undef QUAD
#undef LDS_A0
#undef LDS_A1
#undef LOADB
#undef STAGE_A
#undef BAR

  // epilogue
  const int orow0 = rowBase + wr * WROWS + (lane >> 4) * 4;
  const int ocol0 = colBase + wc * 64 + lr;
#pragma unroll
  for (int ni = 0; ni < 4; ++ni) {
    int n = ocol0 + ni * 16;
    float bv = bias[n];
    float th = 0.f, cc = 0.f;
    if constexpr (FUSED) { th = theta[n]; cc = c1[n]; }
#pragma unroll
    for (int mi = 0; mi < M_REP; ++mi) {
#pragma unroll
      for (int r = 0; r < 4; ++r) {
        size_t m = (size_t)(orow0 + mi * 16 + r);
        float h = acc[mi][ni][r] + bv;
        if constexpr (FUSED) {
          float q = h + cc * __sinf(th + 0.1f * h);
          ((unsigned short*)Cout)[m * N + n] = f2bf(fmaxf(q, 0.f));
        } else {
          ((float*)Cout)[m * N + n] = h;
        }
      }
    }
  }
}

// ---------------- launch ----------------

extern "C" void kernel_launch(void* const* d_in, const int* in_sizes, int n_in,
                              void* d_out, int out_size, void* d_ws,
                              size_t ws_size, hipStream_t stream) {
  const float* x     = (const float*)d_in[0];
  const float* W1    = (const float*)d_in[1];
  const float* b1    = (const float*)d_in[2];
  const float* theta = (const float*)d_in[3];
  const float* qwr   = (const float*)d_in[4];
  const float* qwi   = (const float*)d_in[5];
  const float* W2    = (const float*)d_in[6];
  const float* b2    = (const float*)d_in[7];
  float* out = (float*)d_out;

  const int M = 4 * 2048;            // 8192
  const int DM = 1024, DF = 4096;

  size_t need = ((size_t)96 << 20) + DF * sizeof(float);
  if (ws_size < need) return;

  char* ws = (char*)d_ws;
  unsigned short* xb   = (unsigned short*)ws;                          // 16 MiB
  unsigned short* w1t  = (unsigned short*)(ws + ((size_t)16 << 20));   //  8 MiB
  unsigned short* w2t  = (unsigned short*)(ws + ((size_t)24 << 20));   //  8 MiB
  unsigned short* actb = (unsigned short*)(ws + ((size_t)32 << 20));   // 64 MiB
  float* c1 = (float*)(ws + ((size_t)96 << 20));

  cvt_f32_bf16<<<2048, 256, 0, stream>>>(x, xb, M * DM / 4);
  transpose_cvt<<<dim3(DF / 32, DM / 32), 256, 0, stream>>>(W1, w1t, DM, DF);
  transpose_cvt<<<dim3(DM / 32, DF / 32), 256, 0, stream>>>(W2, w2t, DF, DM);
  qconst<<<DF / 256, 256, 0, stream>>>(theta, qwr, qwi, c1, DF);

  // GEMM1: 8192x4096, K=1024 -> 512 blocks (256x256 tile)
  gemmbr<256, 16, true><<<512, 512, 0, stream>>>(
      xb, w1t, b1, theta, c1, (void*)actb, DF, DF / 256);
  // GEMM2: 8192x1024, K=4096 -> 256 blocks (128x256 tile)
  gemmbr<128, 64, false><<<256, 512, 0, stream>>>(
      actb, w2t, b2, nullptr, nullptr, (void*)out, DM, DM / 256);
}

// Round 8
// 166.056 us; speedup vs baseline: 2.0771x; 2.0771x over previous
//
#include <hip/hip_runtime.h>

typedef __bf16 bf16x8 __attribute__((ext_vector_type(8)));
typedef short  s16x8  __attribute__((ext_vector_type(8)));
typedef float  f32x4  __attribute__((ext_vector_type(4)));

#define DEVINL __device__ __forceinline__

DEVINL unsigned short f2bf(float f) {
  unsigned int u = __builtin_bit_cast(unsigned int, f);
  u += 0x7fffu + ((u >> 16) & 1u);   // round-to-nearest-even
  return (unsigned short)(u >> 16);
}

DEVINL void async16(const void* g, void* l) {
  __builtin_amdgcn_global_load_lds(
      (const __attribute__((address_space(1))) unsigned int*)g,
      (__attribute__((address_space(3))) unsigned int*)l, 16, 0, 0);
}

// ---------------- conversion kernels ----------------

__global__ void cvt_f32_bf16(const float* __restrict__ in,
                             unsigned short* __restrict__ out, int n4) {
  int i = blockIdx.x * blockDim.x + threadIdx.x;
  int stride = gridDim.x * blockDim.x;
  for (; i < n4; i += stride) {
    float4 v = ((const float4*)in)[i];
    ushort4 o;
    o.x = f2bf(v.x); o.y = f2bf(v.y); o.z = f2bf(v.z); o.w = f2bf(v.w);
    ((ushort4*)out)[i] = o;
  }
}

// in: [R][C] fp32  ->  out: [C][R] bf16
__global__ void transpose_cvt(const float* __restrict__ in,
                              unsigned short* __restrict__ out, int R, int C) {
  __shared__ unsigned short tile[32][33];
  int bc = blockIdx.x * 32, br = blockIdx.y * 32;
  int tx = threadIdx.x & 31, ty = threadIdx.x >> 5;
#pragma unroll
  for (int i = 0; i < 32; i += 8)
    tile[ty + i][tx] = f2bf(in[(size_t)(br + ty + i) * C + (bc + tx)]);
  __syncthreads();
#pragma unroll
  for (int i = 0; i < 32; i += 8)
    out[(size_t)(bc + ty + i) * R + (br + tx)] = tile[tx][ty + i];
}

__global__ void qconst(const float* __restrict__ theta,
                       const float* __restrict__ wre,
                       const float* __restrict__ wim,
                       float* __restrict__ c1, int n) {
  int i = blockIdx.x * blockDim.x + threadIdx.x;
  if (i < n) {
    float t = theta[i];
    c1[i] = (cosf(t) * wre[i] + sinf(t) * wim[i]) * wim[i] * 0.1f;
  }
}

// ---------- m201-style 8-phase GEMM: C = A[M][K] * Bt[N][K]^T ----------
// BM x 256 tile, BK=64, 8 waves (2M x 4N), per-wave out (BM/2) x 64.
// Per K-tile: 4 phases, each { ds_reads; stage ONE 16KB unit (2 gload_lds);
//   BAR; lgkmcnt(0); setprio(1); quadrant MFMAs; setprio(0); BAR }.
// Quadrant order (M0,N0),(M0,N1),(M1,N1),(M1,N0): A-set reloaded at P1/P3,
// BOTH B-half sets stay live -> reads/phase = 12,4,8,0 (BM=256).
// Stage stream (1 unit/phase, unit X(S) -> LDS parity S&1):
//   P1(S): A-unit0(S+1)   [A1st(parity^1) last read P3(S-1), drained]
//   P2(S): A-unit1(S+1)
//   P3(S): B-unit0(S+2)   [B(parity) fully reg-loaded by P2(S), drained]
//   P4(S): B-unit1(S+2)
// vmcnt ledger (per-wave FIFO): at P4(S) the newest loads are P3+P4 stages
//   (4). vmcnt(4) therefore certifies A(S+1) (issued P1/P2) and prologue/B
//   units staged earlier -> everything tile S+1 needs. Tail: when S+2 >= NT
//   the P3/P4 stages are skipped -> vmcnt(0) instead; last tile: none.
// WAR safety: every phase's ds_reads are drained by that phase's lgkmcnt(0),
//   which precedes its closing BAR; any overwriting stage is issued only
//   after a later BAR. No sched_barrier anywhere (compiler tracks its own
//   ds_read->MFMA deps with fine-grained waits).
// Swizzle: LDS(row, slot) = G(row, slot ^ (row&7)) via pre-swizzled global
//   source; reads XOR the same mask -> 0 bank conflicts (verified R3/R4).

template <int BM, int NT, bool FUSED>
__global__ __launch_bounds__(512, 2) void gemm8(
    const unsigned short* __restrict__ A,
    const unsigned short* __restrict__ Bt,
    const float* __restrict__ bias,
    const float* __restrict__ theta,
    const float* __restrict__ c1,
    void* __restrict__ Cout,
    int N, int nTilesN) {
  constexpr int K      = NT * 64;
  constexpr int WROWS  = BM / 2;        // per-wave output rows
  constexpr int M_REP  = WROWS / 16;    // 8 (BM=256) or 4 (BM=128)
  constexpr int MH     = M_REP / 2;
  constexpr int ABYTES = BM * 128;      // A bytes per K-tile (32K / 16K)
  constexpr int AH     = ABYTES / 2;    // A unit (16K / 8K)
  constexpr int AL     = AH / 8192;     // gload_lds per A unit (2 / 1)
  constexpr int BUFSZ  = ABYTES + 32768;
  static_assert(AL == 2 || AL == 1, "geometry");

  __shared__ __align__(16) char lds[2 * BUFSZ];

  // bijective XCD swizzle (grid % 8 == 0 for both instantiations)
  int nwg = gridDim.x;
  int wg = blockIdx.x;
  int sw = (wg & 7) * (nwg >> 3) + (wg >> 3);
  int rowBase = (sw / nTilesN) * BM;
  int colBase = (sw % nTilesN) * 256;

  const int t = threadIdx.x;
  const int lane = t & 63;
  const int wid = t >> 6;
  const int wr = wid >> 2, wc = wid & 3;   // 2M x 4N waves
  const int lr = lane & 15;
  const int lg = lane >> 4;                // 0..3
  const int r7 = lane & 7;

  // staging source (pre-swizzled global address, linear LDS dest)
  const int srow = t >> 3;                              // 0..63
  const int scolB = ((t & 7) * 16) ^ ((srow & 7) << 4); // swizzled byte col
  const unsigned short* aSrcB = A  + (size_t)(rowBase + srow) * K + (scolB >> 1);
  const unsigned short* bSrcB = Bt + (size_t)(colBase + srow) * K + (scolB >> 1);

  // swizzled ds_read bases (bytes); frag +2048/row16, ks toggles ^(ks<<6)
  const int aRd = (wr * WROWS + lr) * 128 + ((lg ^ r7) << 4);
  const int bRd = ABYTES + (wc * 64 + lr) * 128 + ((lg ^ r7) << 4);

  f32x4 acc[M_REP][4] = {};
  bf16x8 a[MH][2], b[4][2];

  // ---- macros (all indices compile-time; parity passed as literal) ----
#define STAGE_AU(S, U, P) do {                                              \
    _Pragma("unroll") for (int j = 0; j < AL; ++j)                          \
      async16(aSrcB + ((size_t)((U) * WROWS + j * 64) * K + (size_t)(S) * 64),\
              &lds[(P) * BUFSZ + (U) * AH + j * 8192 + t * 16]);            \
  } while (0)
#define STAGE_BU(S, U, P) do {                                              \
    _Pragma("unroll") for (int j = 0; j < 2; ++j)                           \
      async16(bSrcB + ((size_t)((U) * 128 + j * 64) * K + (size_t)(S) * 64),\
              &lds[(P) * BUFSZ + ABYTES + (U) * 16384 + j * 8192 + t * 16]);\
  } while (0)

#define LOAD_A(MHh, P)                                                      \
  _Pragma("unroll") for (int mi = 0; mi < MH; ++mi)                         \
  _Pragma("unroll") for (int ks = 0; ks < 2; ++ks)                          \
    a[mi][ks] = __builtin_bit_cast(bf16x8, *(const s16x8*)&lds[             \
        (P) * BUFSZ + ((aRd + ((MHh) * MH + mi) * 2048) ^ (ks << 6))])
#define LOAD_B(NHh, P)                                                      \
  _Pragma("unroll") for (int nn = 0; nn < 2; ++nn)                          \
  _Pragma("unroll") for (int ks = 0; ks < 2; ++ks)                          \
    b[(NHh) * 2 + nn][ks] = __builtin_bit_cast(bf16x8, *(const s16x8*)&lds[ \
        (P) * BUFSZ + ((bRd + ((NHh) * 2 + nn) * 2048) ^ (ks << 6))])

#define QUAD(MHh, NHh)                                                      \
  __builtin_amdgcn_s_setprio(1);                                            \
  _Pragma("unroll") for (int mi = 0; mi < MH; ++mi)                         \
  _Pragma("unroll") for (int nn = 0; nn < 2; ++nn)                          \
  _Pragma("unroll") for (int ks = 0; ks < 2; ++ks)                          \
    acc[(MHh) * MH + mi][(NHh) * 2 + nn] =                                  \
        __builtin_amdgcn_mfma_f32_16x16x32_bf16(                            \
            a[mi][ks], b[(NHh) * 2 + nn][ks],                               \
            acc[(MHh) * MH + mi][(NHh) * 2 + nn], 0, 0, 0);                 \
  __builtin_amdgcn_s_setprio(0)

#define BAR() __builtin_amdgcn_s_barrier()
#define LG0() asm volatile("s_waitcnt lgkmcnt(0)" ::: "memory")

#define TILE(T, P) do {                                                     \
    /* phase 1: (M0,N0) */                                                  \
    LOAD_A(0, P); LOAD_B(0, P);                                             \
    if ((T) + 1 < NT) STAGE_AU((T) + 1, 0, (P) ^ 1);                        \
    if (MH == 4) asm volatile("s_waitcnt lgkmcnt(8)" ::: "memory");         \
    BAR(); LG0(); QUAD(0, 0); BAR();                                        \
    /* phase 2: (M0,N1) */                                                  \
    LOAD_B(1, P);                                                           \
    if ((T) + 1 < NT) STAGE_AU((T) + 1, 1, (P) ^ 1);                        \
    BAR(); LG0(); QUAD(0, 1); BAR();                                        \
    /* phase 3: (M1,N1) */                                                  \
    LOAD_A(1, P);                                                           \
    if ((T) + 2 < NT) STAGE_BU((T) + 2, 0, P);                              \
    BAR(); LG0(); QUAD(1, 1); BAR();                                        \
    /* phase 4: (M1,N0) — no new ds_reads */                                \
    if ((T) + 2 < NT) STAGE_BU((T) + 2, 1, P);                              \
    BAR(); QUAD(1, 0);                                                      \
    if ((T) + 2 < NT) {                                                     \
      asm volatile("s_waitcnt vmcnt(4)" ::: "memory");                      \
    } else if ((T) + 1 < NT) {                                              \
      asm volatile("s_waitcnt vmcnt(0)" ::: "memory");                      \
    }                                                                       \
    BAR();                                                                  \
  } while (0)

  // prologue: tile0 (A+B) + tile1 B; allow tile1's B (4 loads) in flight
  STAGE_AU(0, 0, 0); STAGE_AU(0, 1, 0);
  STAGE_BU(0, 0, 0); STAGE_BU(0, 1, 0);
  STAGE_BU(1, 0, 1); STAGE_BU(1, 1, 1);
  asm volatile("s_waitcnt vmcnt(4)" ::: "memory");
  BAR();

  for (int T = 0; T < NT; T += 2) {   // NT even (16, 64)
    TILE(T, 0);
    TILE(T + 1, 1);
  }

#undef TILE
#undef QUAD
#undef LOAD_A
#undef LOAD_B
#undef STAGE_AU
#undef STAGE_BU
#undef BAR
#undef LG0

  // epilogue
  const int orow0 = rowBase + wr * WROWS + (lane >> 4) * 4;
  const int ocol0 = colBase + wc * 64 + lr;
#pragma unroll
  for (int ni = 0; ni < 4; ++ni) {
    int n = ocol0 + ni * 16;
    float bv = bias[n];
    float th = 0.f, cc = 0.f;
    if constexpr (FUSED) { th = theta[n]; cc = c1[n]; }
#pragma unroll
    for (int mi = 0; mi < M_REP; ++mi) {
#pragma unroll
      for (int r = 0; r < 4; ++r) {
        size_t m = (size_t)(orow0 + mi * 16 + r);
        float h = acc[mi][ni][r] + bv;
        if constexpr (FUSED) {
          float q = h + cc * __sinf(th + 0.1f * h);
          ((unsigned short*)Cout)[m * N + n] = f2bf(fmaxf(q, 0.f));
        } else {
          ((float*)Cout)[m * N + n] = h;
        }
      }
    }
  }
}

// ---------------- launch ----------------

extern "C" void kernel_launch(void* const* d_in, const int* in_sizes, int n_in,
                              void* d_out, int out_size, void* d_ws,
                              size_t ws_size, hipStream_t stream) {
  const float* x     = (const float*)d_in[0];
  const float* W1    = (const float*)d_in[1];
  const float* b1    = (const float*)d_in[2];
  const float* theta = (const float*)d_in[3];
  const float* qwr   = (const float*)d_in[4];
  const float* qwi   = (const float*)d_in[5];
  const float* W2    = (const float*)d_in[6];
  const float* b2    = (const float*)d_in[7];
  float* out = (float*)d_out;

  const int M = 4 * 2048;            // 8192
  const int DM = 1024, DF = 4096;

  size_t need = ((size_t)96 << 20) + DF * sizeof(float);
  if (ws_size < need) return;

  char* ws = (char*)d_ws;
  unsigned short* xb   = (unsigned short*)ws;                          // 16 MiB
  unsigned short* w1t  = (unsigned short*)(ws + ((size_t)16 << 20));   //  8 MiB
  unsigned short* w2t  = (unsigned short*)(ws + ((size_t)24 << 20));   //  8 MiB
  unsigned short* actb = (unsigned short*)(ws + ((size_t)32 << 20));   // 64 MiB
  float* c1 = (float*)(ws + ((size_t)96 << 20));

  cvt_f32_bf16<<<2048, 256, 0, stream>>>(x, xb, M * DM / 4);
  transpose_cvt<<<dim3(DF / 32, DM / 32), 256, 0, stream>>>(W1, w1t, DM, DF);
  transpose_cvt<<<dim3(DM / 32, DF / 32), 256, 0, stream>>>(W2, w2t, DF, DM);
  qconst<<<DF / 256, 256, 0, stream>>>(theta, qwr, qwi, c1, DF);

  // GEMM1: 8192x4096, K=1024 -> 512 blocks (256x256 tile)
  gemm8<256, 16, true><<<512, 512, 0, stream>>>(
      xb, w1t, b1, theta, c1, (void*)actb, DF, DF / 256);
  // GEMM2: 8192x1024, K=4096 -> 256 blocks (128x256 tile)
  gemm8<128, 64, false><<<256, 512, 0, stream>>>(
      actb, w2t, b2, nullptr, nullptr, (void*)out, DM, DM / 256);
}